// Round 1
// baseline (1229.546 us; speedup 1.0000x reference)
//
#include <hip/hip_runtime.h>
#include <hip/hip_bf16.h>
#include <stdint.h>

#define L_DIM 1024
#define B_DIM 32
#define D_DIM 1024
#define M_DIM (L_DIM * B_DIM)        // 32768 GEMM rows
#define N3_DIM (3 * D_DIM)           // 3072 GEMM cols (u0 | f | r regions)
#define K_DIM D_DIM                  // 1024
#define LBD ((int64_t)L_DIM * B_DIM * D_DIM)  // 33554432

typedef __bf16 bf16_t;
typedef bf16_t bf16x8 __attribute__((ext_vector_type(8)));
typedef float f32x4 __attribute__((ext_vector_type(4)));

// RTNE fp32 -> bf16 (bit trick; inputs are normal floats)
__device__ __forceinline__ unsigned short f2bf(float f) {
    union { float f; unsigned u; } v; v.f = f;
    unsigned u = v.u;
    u += 0x7FFFu + ((u >> 16) & 1u);
    return (unsigned short)(u >> 16);
}

// ---------------- convert x: fp32 [L,B,D] -> bf16 [M,K] ----------------
__global__ void cvt_x_kernel(const float* __restrict__ x, unsigned short* __restrict__ xb) {
    int64_t i0 = ((int64_t)blockIdx.x * blockDim.x + threadIdx.x) * 4;
    int64_t stride = (int64_t)gridDim.x * blockDim.x * 4;
    for (int64_t i = i0; i < LBD; i += stride) {
        float4 v = *reinterpret_cast<const float4*>(x + i);
        ushort4 o;
        o.x = f2bf(v.x); o.y = f2bf(v.y); o.z = f2bf(v.z); o.w = f2bf(v.w);
        *reinterpret_cast<ushort4*>(xb + i) = o;
    }
}

// ------------- convert weight: [i(1024)][o(1024)][k(3)] fp32 -> wT [n=k*1024+o][i] bf16 -------------
__global__ void cvt_w_kernel(const float* __restrict__ w, unsigned short* __restrict__ wT) {
    __shared__ float tile[64][65];
    int bid = blockIdx.x;               // 768 = 3(k) * 16(o-tiles) * 16(i-tiles)
    int k  = bid >> 8;
    int o0 = ((bid >> 4) & 15) * 64;
    int i0 = (bid & 15) * 64;
    int t = threadIdx.x;
    {
        int o = t & 63, ib = t >> 6;
        #pragma unroll
        for (int it = 0; it < 16; ++it) {
            int i = ib + it * 4;
            tile[o][i] = w[((int64_t)(i0 + i) * 1024 + (o0 + o)) * 3 + k];
        }
    }
    __syncthreads();
    {
        int i = t & 63, ob = t >> 6;
        #pragma unroll
        for (int ot = 0; ot < 16; ++ot) {
            int o = ob + ot * 4;
            wT[(int64_t)(k * 1024 + o0 + o) * 1024 + (i0 + i)] = f2bf(tile[o][i]);
        }
    }
}

// ---------------- GEMM: [32768 x 3072] = x_bf16 [32768x1024] @ W [1024x3072] ----------------
// Bt is stored transposed [3072][1024] so both A and B fragments read contiguous K from LDS.
// Epilogue fuses bias + sigmoid and scatters into the three gate arrays.
__device__ __forceinline__ void gload_lds16(const void* g, void* l) {
    __builtin_amdgcn_global_load_lds(
        (const __attribute__((address_space(1))) unsigned int*)g,
        (__attribute__((address_space(3))) unsigned int*)l,
        16, 0, 0);
}

__global__ __launch_bounds__(256, 2) void gemm_kernel(
    const unsigned short* __restrict__ A,    // [32768][1024] bf16 bits
    const unsigned short* __restrict__ Bt,   // [3072][1024] bf16 bits
    const float* __restrict__ bias,          // [2048]
    float* __restrict__ out,                 // d_out: [0,LBD)=f (later h), [LBD,2LBD)=u0 (later c)
    float* __restrict__ r_arr)               // ws: [LBD] r
{
    __shared__ unsigned short a_tile[128 * 64];
    __shared__ unsigned short b_tile[128 * 64];

    int bx = blockIdx.x;
    int nt = bx % 24, mt = bx / 24;          // consecutive blocks share the A panel (L2 reuse)
    int m0 = mt * 128, n0 = nt * 128;

    int tid = threadIdx.x;
    int w = tid >> 6, lane = tid & 63;

    f32x4 zero = {0.f, 0.f, 0.f, 0.f};
    f32x4 acc[4][4];
    #pragma unroll
    for (int i = 0; i < 4; ++i)
        #pragma unroll
        for (int j = 0; j < 4; ++j) acc[i][j] = zero;

    int ar = lane >> 3;                      // row within 8-row group
    int ac = (lane & 7) * 8;                 // bf16 col within 64
    int wr = (w >> 1) * 64, wc = (w & 1) * 64;
    int l15 = lane & 15;
    int kgrp = (lane >> 4) * 8;

    for (int kt = 0; kt < 16; ++kt) {
        int k0 = kt * 64;
        __syncthreads();                     // protect LDS from prior-iter readers
        #pragma unroll
        for (int i = 0; i < 4; ++i) {
            int r0 = (i * 4 + w) * 8;
            gload_lds16(A  + (int64_t)(m0 + r0 + ar) * 1024 + k0 + ac, &a_tile[r0 * 64]);
            gload_lds16(Bt + (int64_t)(n0 + r0 + ar) * 1024 + k0 + ac, &b_tile[r0 * 64]);
        }
        __syncthreads();                     // compiler drains vmcnt before barrier

        #pragma unroll
        for (int ks = 0; ks < 2; ++ks) {
            int kb = ks * 32 + kgrp;
            bf16x8 af[4], bf[4];
            #pragma unroll
            for (int im = 0; im < 4; ++im)
                af[im] = *reinterpret_cast<const bf16x8*>(&a_tile[(wr + im * 16 + l15) * 64 + kb]);
            #pragma unroll
            for (int in_ = 0; in_ < 4; ++in_)
                bf[in_] = *reinterpret_cast<const bf16x8*>(&b_tile[(wc + in_ * 16 + l15) * 64 + kb]);
            #pragma unroll
            for (int im = 0; im < 4; ++im)
                #pragma unroll
                for (int in_ = 0; in_ < 4; ++in_)
                    acc[im][in_] = __builtin_amdgcn_mfma_f32_16x16x32_bf16(
                        af[im], bf[in_], acc[im][in_], 0, 0, 0);
        }
    }

    // epilogue: region is block-uniform since BN=128 divides 1024
    int region = n0 >> 10;
    #pragma unroll
    for (int im = 0; im < 4; ++im) {
        #pragma unroll
        for (int in_ = 0; in_ < 4; ++in_) {
            f32x4 v = acc[im][in_];
            int row0 = wr + im * 16 + ((lane >> 4) << 2);
            int col = wc + in_ * 16 + l15;
            int o = (n0 + col) & 1023;
            #pragma unroll
            for (int j = 0; j < 4; ++j) {
                int64_t mi = m0 + row0 + j;
                int64_t idx = mi * 1024 + o;
                float val = v[j];
                if (region == 0) {
                    out[LBD + idx] = val;                                  // u0
                } else if (region == 1) {
                    out[idx] = 1.0f / (1.0f + __expf(-(val + bias[o])));   // f
                } else {
                    r_arr[idx] = 1.0f / (1.0f + __expf(-(val + bias[1024 + o]))); // r
                }
            }
        }
    }
}

// ---------------- sequential scan over L; in-place f->h, u0->c ----------------
__global__ void scan_kernel(const float* __restrict__ x, const float* __restrict__ c0,
                            const float* __restrict__ r_arr,
                            float* __restrict__ out_h, float* __restrict__ out_c) {
    int idx = blockIdx.x * blockDim.x + threadIdx.x;   // 0..32767 = b*1024 + d
    float c = c0[idx];
    int64_t base = idx;
    #pragma unroll 4
    for (int l = 0; l < L_DIM; ++l, base += (int64_t)B_DIM * D_DIM) {
        float f  = out_h[base];     // f written by gemm epilogue
        float u0 = out_c[base];     // u0 written by gemm epilogue
        c = u0 + f * (c - u0);      // f*c + (1-f)*u0
        out_c[base] = c;
        float g = tanhf(c);
        float r = r_arr[base];
        float xv = x[base];
        out_h[base] = xv + r * (g - xv);
    }
}

extern "C" void kernel_launch(void* const* d_in, const int* in_sizes, int n_in,
                              void* d_out, int out_size, void* d_ws, size_t ws_size,
                              hipStream_t stream) {
    const float* x    = (const float*)d_in[0];
    const float* c0   = (const float*)d_in[1];
    const float* wgt  = (const float*)d_in[2];
    const float* bias = (const float*)d_in[3];
    float* out = (float*)d_out;

    unsigned short* xb = (unsigned short*)d_ws;                 // 64 MB
    unsigned short* wT = xb + (int64_t)M_DIM * K_DIM;           // +6 MB
    float* r_arr = (float*)(wT + (int64_t)N3_DIM * K_DIM);      // +128 MB

    cvt_x_kernel<<<8192, 256, 0, stream>>>(x, xb);
    cvt_w_kernel<<<768, 256, 0, stream>>>(wgt, wT);
    gemm_kernel<<<6144, 256, 0, stream>>>(xb, wT, bias, out, r_arr);
    scan_kernel<<<512, 64, 0, stream>>>(x, c0, r_arr, out, out + LBD);
}

// Round 2
// 601.047 us; speedup vs baseline: 2.0457x; 2.0457x over previous
//
#include <hip/hip_runtime.h>
#include <hip/hip_bf16.h>
#include <stdint.h>

#define L_DIM 1024
#define B_DIM 32
#define D_DIM 1024
#define M_DIM (L_DIM * B_DIM)        // 32768 GEMM rows
#define N3_DIM (3 * D_DIM)           // 3072 GEMM cols (u0 | f | r regions)
#define K_DIM D_DIM                  // 1024
#define LBD ((int64_t)L_DIM * B_DIM * D_DIM)  // 33554432
#define NBD (B_DIM * D_DIM)          // 32768 chains
#define NCHUNK 32
#define CLEN 32

typedef __bf16 bf16_t;
typedef bf16_t bf16x8 __attribute__((ext_vector_type(8)));
typedef float f32x4 __attribute__((ext_vector_type(4)));

// RTNE fp32 -> bf16 (bit trick; inputs are normal floats)
__device__ __forceinline__ unsigned short f2bf(float f) {
    union { float f; unsigned u; } v; v.f = f;
    unsigned u = v.u;
    u += 0x7FFFu + ((u >> 16) & 1u);
    return (unsigned short)(u >> 16);
}

// ---------------- convert x: fp32 [L,B,D] -> bf16 [M,K] ----------------
__global__ void cvt_x_kernel(const float* __restrict__ x, unsigned short* __restrict__ xb) {
    int64_t i0 = ((int64_t)blockIdx.x * blockDim.x + threadIdx.x) * 4;
    int64_t stride = (int64_t)gridDim.x * blockDim.x * 4;
    for (int64_t i = i0; i < LBD; i += stride) {
        float4 v = *reinterpret_cast<const float4*>(x + i);
        ushort4 o;
        o.x = f2bf(v.x); o.y = f2bf(v.y); o.z = f2bf(v.z); o.w = f2bf(v.w);
        *reinterpret_cast<ushort4*>(xb + i) = o;
    }
}

// ------------- convert weight: [i(1024)][o(1024)][k(3)] fp32 -> wT [n=k*1024+o][i] bf16 -------------
__global__ void cvt_w_kernel(const float* __restrict__ w, unsigned short* __restrict__ wT) {
    __shared__ float tile[64][65];
    int bid = blockIdx.x;               // 768 = 3(k) * 16(o-tiles) * 16(i-tiles)
    int k  = bid >> 8;
    int o0 = ((bid >> 4) & 15) * 64;
    int i0 = (bid & 15) * 64;
    int t = threadIdx.x;
    {
        int o = t & 63, ib = t >> 6;
        #pragma unroll
        for (int it = 0; it < 16; ++it) {
            int i = ib + it * 4;
            tile[o][i] = w[((int64_t)(i0 + i) * 1024 + (o0 + o)) * 3 + k];
        }
    }
    __syncthreads();
    {
        int i = t & 63, ob = t >> 6;
        #pragma unroll
        for (int ot = 0; ot < 16; ++ot) {
            int o = ob + ot * 4;
            wT[(int64_t)(k * 1024 + o0 + o) * 1024 + (i0 + i)] = f2bf(tile[o][i]);
        }
    }
}

// ---------------- GEMM: [32768 x 3072] = x_bf16 [32768x1024] @ W [1024x3072] ----------------
__device__ __forceinline__ void gload_lds16(const void* g, void* l) {
    __builtin_amdgcn_global_load_lds(
        (const __attribute__((address_space(1))) unsigned int*)g,
        (__attribute__((address_space(3))) unsigned int*)l,
        16, 0, 0);
}

__global__ __launch_bounds__(256, 2) void gemm_kernel(
    const unsigned short* __restrict__ A,    // [32768][1024] bf16 bits
    const unsigned short* __restrict__ Bt,   // [3072][1024] bf16 bits
    const float* __restrict__ bias,          // [2048]
    float* __restrict__ out,                 // d_out: [0,LBD)=f (later h), [LBD,2LBD)=u0 (later c)
    float* __restrict__ r_arr)               // ws: [LBD] r
{
    __shared__ unsigned short a_tile[128 * 64];
    __shared__ unsigned short b_tile[128 * 64];

    int bx = blockIdx.x;
    int nt = bx % 24, mt = bx / 24;          // consecutive blocks share the A panel (L2 reuse)
    int m0 = mt * 128, n0 = nt * 128;

    int tid = threadIdx.x;
    int w = tid >> 6, lane = tid & 63;

    f32x4 zero = {0.f, 0.f, 0.f, 0.f};
    f32x4 acc[4][4];
    #pragma unroll
    for (int i = 0; i < 4; ++i)
        #pragma unroll
        for (int j = 0; j < 4; ++j) acc[i][j] = zero;

    int ar = lane >> 3;                      // row within 8-row group
    int ac = (lane & 7) * 8;                 // bf16 col within 64
    int wr = (w >> 1) * 64, wc = (w & 1) * 64;
    int l15 = lane & 15;
    int kgrp = (lane >> 4) * 8;

    for (int kt = 0; kt < 16; ++kt) {
        int k0 = kt * 64;
        __syncthreads();                     // protect LDS from prior-iter readers
        #pragma unroll
        for (int i = 0; i < 4; ++i) {
            int r0 = (i * 4 + w) * 8;
            gload_lds16(A  + (int64_t)(m0 + r0 + ar) * 1024 + k0 + ac, &a_tile[r0 * 64]);
            gload_lds16(Bt + (int64_t)(n0 + r0 + ar) * 1024 + k0 + ac, &b_tile[r0 * 64]);
        }
        __syncthreads();

        #pragma unroll
        for (int ks = 0; ks < 2; ++ks) {
            int kb = ks * 32 + kgrp;
            bf16x8 af[4], bf[4];
            #pragma unroll
            for (int im = 0; im < 4; ++im)
                af[im] = *reinterpret_cast<const bf16x8*>(&a_tile[(wr + im * 16 + l15) * 64 + kb]);
            #pragma unroll
            for (int in_ = 0; in_ < 4; ++in_)
                bf[in_] = *reinterpret_cast<const bf16x8*>(&b_tile[(wc + in_ * 16 + l15) * 64 + kb]);
            #pragma unroll
            for (int im = 0; im < 4; ++im)
                #pragma unroll
                for (int in_ = 0; in_ < 4; ++in_)
                    acc[im][in_] = __builtin_amdgcn_mfma_f32_16x16x32_bf16(
                        af[im], bf[in_], acc[im][in_], 0, 0, 0);
        }
    }

    // epilogue: region is block-uniform since BN=128 divides 1024
    int region = n0 >> 10;
    #pragma unroll
    for (int im = 0; im < 4; ++im) {
        #pragma unroll
        for (int in_ = 0; in_ < 4; ++in_) {
            f32x4 v = acc[im][in_];
            int row0 = wr + im * 16 + ((lane >> 4) << 2);
            int col = wc + in_ * 16 + l15;
            int o = (n0 + col) & 1023;
            #pragma unroll
            for (int j = 0; j < 4; ++j) {
                int64_t mi = m0 + row0 + j;
                int64_t idx = mi * 1024 + o;
                float val = v[j];
                if (region == 0) {
                    out[LBD + idx] = val;                                  // u0
                } else if (region == 1) {
                    out[idx] = 1.0f / (1.0f + __expf(-(val + bias[o])));   // f
                } else {
                    r_arr[idx] = 1.0f / (1.0f + __expf(-(val + bias[1024 + o]))); // r
                }
            }
        }
    }
}

// ---------------- chunked parallel scan ----------------
// c_t = f_t*c_{t-1} + (1-f_t)*u0_t. Chunk transfer: c_out = A*c_in + B.

// Phase 1: per (chunk, b, d): A = prod f, B = local scan from 0.
__global__ void scan_phase1(const float* __restrict__ f_arr, const float* __restrict__ u0_arr,
                            float* __restrict__ Aout, float* __restrict__ Bout) {
    int t = blockIdx.x * blockDim.x + threadIdx.x;   // chunk*NBD + idx
    int idx = t & (NBD - 1);
    int chunk = t >> 15;
    int64_t base = (int64_t)chunk * CLEN * NBD + idx;
    float Ap = 1.0f, Bv = 0.0f;
    #pragma unroll 8
    for (int i = 0; i < CLEN; ++i, base += NBD) {
        float f = f_arr[base];
        float u0 = u0_arr[base];
        Bv = u0 + f * (Bv - u0);
        Ap *= f;
    }
    Aout[t] = Ap; Bout[t] = Bv;
}

// Phase 2: sequential combine over chunks -> c_in per chunk.
__global__ void scan_phase2(const float* __restrict__ c0, const float* __restrict__ Aarr,
                            const float* __restrict__ Barr, float* __restrict__ cin) {
    int idx = blockIdx.x * blockDim.x + threadIdx.x; // 0..NBD-1
    float c = c0[idx];
    #pragma unroll
    for (int ch = 0; ch < NCHUNK; ++ch) {
        cin[ch * NBD + idx] = c;
        c = Aarr[ch * NBD + idx] * c + Barr[ch * NBD + idx];
    }
}

// Phase 3: re-scan each chunk from its true c_in; fused tanh + highway; in-place f->h, u0->c.
__global__ void scan_phase3(const float* __restrict__ x, const float* __restrict__ r_arr,
                            const float* __restrict__ cin,
                            float* out_h, float* out_c) {
    int t = blockIdx.x * blockDim.x + threadIdx.x;
    int idx = t & (NBD - 1);
    int chunk = t >> 15;
    float c = cin[t];
    int64_t base = (int64_t)chunk * CLEN * NBD + idx;
    #pragma unroll 4
    for (int i = 0; i < CLEN; ++i, base += NBD) {
        float f  = out_h[base];     // f written by gemm epilogue
        float u0 = out_c[base];     // u0 written by gemm epilogue
        c = u0 + f * (c - u0);      // f*c + (1-f)*u0
        out_c[base] = c;
        float e = __expf(2.0f * c); // tanh via exp; |c| <~ 6 so no overflow
        float g = (e - 1.0f) / (e + 1.0f);
        float r = r_arr[base];
        float xv = x[base];
        out_h[base] = xv + r * (g - xv);
    }
}

extern "C" void kernel_launch(void* const* d_in, const int* in_sizes, int n_in,
                              void* d_out, int out_size, void* d_ws, size_t ws_size,
                              hipStream_t stream) {
    const float* x    = (const float*)d_in[0];
    const float* c0   = (const float*)d_in[1];
    const float* wgt  = (const float*)d_in[2];
    const float* bias = (const float*)d_in[3];
    float* out = (float*)d_out;

    unsigned short* xb = (unsigned short*)d_ws;                 // 64 MB (dead after gemm)
    unsigned short* wT = xb + (int64_t)M_DIM * K_DIM;           // +6 MB
    float* r_arr = (float*)(wT + (int64_t)N3_DIM * K_DIM);      // +128 MB

    // A/B/cin overlay the xb region (xb is dead once gemm completes)
    float* Aarr = (float*)d_ws;                                 // 4 MB
    float* Barr = Aarr + NCHUNK * NBD;                          // 4 MB
    float* cin  = Barr + NCHUNK * NBD;                          // 4 MB

    cvt_x_kernel<<<8192, 256, 0, stream>>>(x, xb);
    cvt_w_kernel<<<768, 256, 0, stream>>>(wgt, wT);
    gemm_kernel<<<6144, 256, 0, stream>>>(xb, wT, bias, out, r_arr);
    scan_phase1<<<(NCHUNK * NBD) / 256, 256, 0, stream>>>(out, out + LBD, Aarr, Barr);
    scan_phase2<<<NBD / 256, 256, 0, stream>>>(c0, Aarr, Barr, cin);
    scan_phase3<<<(NCHUNK * NBD) / 256, 256, 0, stream>>>(x, r_arr, cin, out, out + LBD);
}

// Round 3
// 560.068 us; speedup vs baseline: 2.1954x; 1.0732x over previous
//
#include <hip/hip_runtime.h>
#include <hip/hip_bf16.h>
#include <stdint.h>

#define L_DIM 1024
#define B_DIM 32
#define D_DIM 1024
#define M_DIM (L_DIM * B_DIM)        // 32768 GEMM rows
#define N3_DIM (3 * D_DIM)           // 3072 GEMM cols (u0 | f | r regions)
#define K_DIM D_DIM                  // 1024
#define LBD ((int64_t)L_DIM * B_DIM * D_DIM)  // 33554432
#define NBD (B_DIM * D_DIM)          // 32768 chains
#define NCHUNK 32
#define CLEN 32

// GEMM tiling
#define BM 256
#define BN 256
#define BK 64
#define NMT (M_DIM / BM)   // 128
#define NNT (N3_DIM / BN)  // 12
#define NKT (K_DIM / BK)   // 16

typedef __bf16 bf16_t;
typedef bf16_t bf16x8 __attribute__((ext_vector_type(8)));
typedef float f32x4 __attribute__((ext_vector_type(4)));

// RTNE fp32 -> bf16 bits
__device__ __forceinline__ unsigned short f2bf(float f) {
    union { float f; unsigned u; } v; v.f = f;
    unsigned u = v.u;
    u += 0x7FFFu + ((u >> 16) & 1u);
    return (unsigned short)(u >> 16);
}
__device__ __forceinline__ float bf2f(unsigned short h) {
    union { unsigned u; float f; } v; v.u = ((unsigned)h) << 16;
    return v.f;
}

// ---------------- convert x: fp32 [L,B,D] -> bf16 [M,K] ----------------
__global__ void cvt_x_kernel(const float* __restrict__ x, unsigned short* __restrict__ xb) {
    int64_t i0 = ((int64_t)blockIdx.x * blockDim.x + threadIdx.x) * 4;
    int64_t stride = (int64_t)gridDim.x * blockDim.x * 4;
    for (int64_t i = i0; i < LBD; i += stride) {
        float4 v = *reinterpret_cast<const float4*>(x + i);
        ushort4 o;
        o.x = f2bf(v.x); o.y = f2bf(v.y); o.z = f2bf(v.z); o.w = f2bf(v.w);
        *reinterpret_cast<ushort4*>(xb + i) = o;
    }
}

// ------------- convert weight: [i(1024)][o(1024)][k(3)] fp32 -> wT [n=k*1024+o][i] bf16 -------------
__global__ void cvt_w_kernel(const float* __restrict__ w, unsigned short* __restrict__ wT) {
    __shared__ float tile[64][65];
    int bid = blockIdx.x;               // 768 = 3(k) * 16(o-tiles) * 16(i-tiles)
    int k  = bid >> 8;
    int o0 = ((bid >> 4) & 15) * 64;
    int i0 = (bid & 15) * 64;
    int t = threadIdx.x;
    {
        int o = t & 63, ib = t >> 6;
        #pragma unroll
        for (int it = 0; it < 16; ++it) {
            int i = ib + it * 4;
            tile[o][i] = w[((int64_t)(i0 + i) * 1024 + (o0 + o)) * 3 + k];
        }
    }
    __syncthreads();
    {
        int i = t & 63, ob = t >> 6;
        #pragma unroll
        for (int ot = 0; ot < 16; ++ot) {
            int o = ob + ot * 4;
            wT[(int64_t)(k * 1024 + o0 + o) * 1024 + (i0 + i)] = f2bf(tile[o][i]);
        }
    }
}

// ---------------- GEMM: 256x256 tile, 8 waves, dbuf LDS, counted vmcnt, T2 swizzle ----------------
__device__ __forceinline__ void gload_lds16(const void* g, void* l) {
    __builtin_amdgcn_global_load_lds(
        (const __attribute__((address_space(1))) unsigned int*)g,
        (__attribute__((address_space(3))) unsigned int*)l,
        16, 0, 0);
}

__global__ __launch_bounds__(512, 2) void gemm_kernel(
    const unsigned short* __restrict__ A,    // [32768][1024] bf16 bits
    const unsigned short* __restrict__ Bt,   // [3072][1024] bf16 bits
    const float* __restrict__ bias,          // [2048]
    float* __restrict__ u0_out,              // d_out + LBD: u0 fp32
    unsigned short* __restrict__ fb,         // ws: f bf16
    unsigned short* __restrict__ rb)         // ws: r bf16
{
    // 128 KiB LDS: double-buffered 256x64 A and B tiles (gfx950 has 160 KiB/CU)
    __shared__ unsigned short a_lds[2][BM * BK];
    __shared__ unsigned short b_lds[2][BM * BK];

    int bid = blockIdx.x;
    // XCD-aware swizzle (1536 % 8 == 0 -> simple form is bijective); n-fast within XCD chunk
    int swz = (bid & 7) * (NMT * NNT / 8) + (bid >> 3);
    int nt = swz % NNT, mt = swz / NNT;
    int m0 = mt * BM, n0 = nt * BN;

    int tid = threadIdx.x;
    int w = tid >> 6, lane = tid & 63;
    int wm = w >> 2, wn = w & 3;           // 2 (M) x 4 (N) wave grid; per-wave out 128x64
    int l15 = lane & 15, l4 = lane >> 4;

    // Staging: each wave stages a 32-row slab of A and of B per K-tile (4 gload_lds each).
    // LDS dest is linear (base + lane*16); source column is pre-swizzled: chunk ^= (row&7).
    int sr = lane >> 3;                     // row within 8-row group
    int scol = ((lane & 7) ^ sr) << 3;      // swizzled 16B-chunk, in bf16 elements
    const unsigned short* Abase = A  + (int64_t)(m0 + w * 32 + sr) * K_DIM + scol;
    const unsigned short* Bbase = Bt + (int64_t)(n0 + w * 32 + sr) * K_DIM + scol;

    f32x4 acc[8][4];
    #pragma unroll
    for (int i = 0; i < 8; ++i)
        #pragma unroll
        for (int j = 0; j < 4; ++j) acc[i][j] = (f32x4){0.f, 0.f, 0.f, 0.f};

    // prologue: stage K-tiles 0 and 1 (8 loads/thread each)
    #pragma unroll
    for (int i = 0; i < 4; ++i) {
        gload_lds16(Abase + (int64_t)i * 8 * K_DIM,      &a_lds[0][(w * 32 + i * 8) * BK]);
        gload_lds16(Bbase + (int64_t)i * 8 * K_DIM,      &b_lds[0][(w * 32 + i * 8) * BK]);
    }
    #pragma unroll
    for (int i = 0; i < 4; ++i) {
        gload_lds16(Abase + (int64_t)i * 8 * K_DIM + BK, &a_lds[1][(w * 32 + i * 8) * BK]);
        gload_lds16(Bbase + (int64_t)i * 8 * K_DIM + BK, &b_lds[1][(w * 32 + i * 8) * BK]);
    }

    #pragma unroll
    for (int kt = 0; kt < NKT; ++kt) {
        int cur = kt & 1;
        // tile kt's 8 loads are the oldest outstanding; don't drain the prefetch
        if (kt < NKT - 1) asm volatile("s_waitcnt vmcnt(8)" ::: "memory");
        else              asm volatile("s_waitcnt vmcnt(0)" ::: "memory");
        __builtin_amdgcn_s_barrier();
        asm volatile("" ::: "memory");

        const unsigned short* al = a_lds[cur];
        const unsigned short* bl = b_lds[cur];
        __builtin_amdgcn_s_setprio(1);
        #pragma unroll
        for (int ks = 0; ks < 2; ++ks) {
            // logical chunk = ks*4 + l4; physical = chunk ^ (row&7), row&7 == l15&7
            int pc = (((ks * 4 + l4) ^ (l15 & 7)) << 3);
            bf16x8 bfr[4];
            #pragma unroll
            for (int j = 0; j < 4; ++j)
                bfr[j] = *reinterpret_cast<const bf16x8*>(&bl[(wn * 64 + j * 16 + l15) * BK + pc]);
            #pragma unroll
            for (int i = 0; i < 8; ++i) {
                bf16x8 afr = *reinterpret_cast<const bf16x8*>(&al[(wm * 128 + i * 16 + l15) * BK + pc]);
                #pragma unroll
                for (int j = 0; j < 4; ++j)
                    acc[i][j] = __builtin_amdgcn_mfma_f32_16x16x32_bf16(afr, bfr[j], acc[i][j], 0, 0, 0);
            }
        }
        __builtin_amdgcn_s_setprio(0);
        asm volatile("" ::: "memory");
        __builtin_amdgcn_s_barrier();   // all waves done reading buf[cur] before restaging it

        if (kt + 2 < NKT) {
            int64_t k0 = (int64_t)(kt + 2) * BK;
            #pragma unroll
            for (int i = 0; i < 4; ++i) {
                gload_lds16(Abase + (int64_t)i * 8 * K_DIM + k0, &a_lds[cur][(w * 32 + i * 8) * BK]);
                gload_lds16(Bbase + (int64_t)i * 8 * K_DIM + k0, &b_lds[cur][(w * 32 + i * 8) * BK]);
            }
        }
    }

    // epilogue: region uniform per block (BN=256 divides 1024)
    int region = n0 >> 10;
    #pragma unroll
    for (int i = 0; i < 8; ++i) {
        #pragma unroll
        for (int j = 0; j < 4; ++j) {
            f32x4 v = acc[i][j];
            int row0 = m0 + wm * 128 + i * 16 + l4 * 4;
            int col  = (n0 + wn * 64 + j * 16 + l15) & 1023;
            #pragma unroll
            for (int jj = 0; jj < 4; ++jj) {
                int64_t idx = (int64_t)(row0 + jj) * 1024 + col;
                float val = v[jj];
                if (region == 0) {
                    u0_out[idx] = val;
                } else if (region == 1) {
                    fb[idx] = f2bf(1.0f / (1.0f + __expf(-(val + bias[col]))));
                } else {
                    rb[idx] = f2bf(1.0f / (1.0f + __expf(-(val + bias[1024 + col]))));
                }
            }
        }
    }
}

// ---------------- chunked parallel scan ----------------
// c_t = f_t*c_{t-1} + (1-f_t)*u0_t. Chunk transfer: c_out = A*c_in + B.

__global__ void scan_phase1(const unsigned short* __restrict__ fb,
                            const float* __restrict__ u0_arr,
                            float* __restrict__ Aout, float* __restrict__ Bout) {
    int t = blockIdx.x * blockDim.x + threadIdx.x;   // chunk*NBD + idx
    int idx = t & (NBD - 1);
    int chunk = t >> 15;
    int64_t base = (int64_t)chunk * CLEN * NBD + idx;
    float Ap = 1.0f, Bv = 0.0f;
    #pragma unroll 8
    for (int i = 0; i < CLEN; ++i, base += NBD) {
        float f = bf2f(fb[base]);
        float u0 = u0_arr[base];
        Bv = u0 + f * (Bv - u0);
        Ap *= f;
    }
    Aout[t] = Ap; Bout[t] = Bv;
}

__global__ void scan_phase2(const float* __restrict__ c0, const float* __restrict__ Aarr,
                            const float* __restrict__ Barr, float* __restrict__ cin) {
    int idx = blockIdx.x * blockDim.x + threadIdx.x; // 0..NBD-1
    float c = c0[idx];
    #pragma unroll
    for (int ch = 0; ch < NCHUNK; ++ch) {
        cin[ch * NBD + idx] = c;
        c = Aarr[ch * NBD + idx] * c + Barr[ch * NBD + idx];
    }
}

__global__ void scan_phase3(const float* __restrict__ x,
                            const unsigned short* __restrict__ fb,
                            const unsigned short* __restrict__ rb,
                            const float* __restrict__ cin,
                            float* __restrict__ out_h, float* __restrict__ out_c) {
    int t = blockIdx.x * blockDim.x + threadIdx.x;
    int idx = t & (NBD - 1);
    int chunk = t >> 15;
    float c = cin[t];
    int64_t base = (int64_t)chunk * CLEN * NBD + idx;
    #pragma unroll 4
    for (int i = 0; i < CLEN; ++i, base += NBD) {
        float f  = bf2f(fb[base]);
        float u0 = out_c[base];     // u0 written by gemm epilogue
        c = u0 + f * (c - u0);      // f*c + (1-f)*u0
        out_c[base] = c;
        float e = __expf(2.0f * c); // tanh via exp; |c| bounded so no overflow
        float g = (e - 1.0f) / (e + 1.0f);
        float r = bf2f(rb[base]);
        float xv = x[base];
        out_h[base] = xv + r * (g - xv);
    }
}

extern "C" void kernel_launch(void* const* d_in, const int* in_sizes, int n_in,
                              void* d_out, int out_size, void* d_ws, size_t ws_size,
                              hipStream_t stream) {
    const float* x    = (const float*)d_in[0];
    const float* c0   = (const float*)d_in[1];
    const float* wgt  = (const float*)d_in[2];
    const float* bias = (const float*)d_in[3];
    float* out = (float*)d_out;

    unsigned short* xb = (unsigned short*)d_ws;                 // 64 MB (dead after gemm)
    unsigned short* wT = xb + (int64_t)M_DIM * K_DIM;           // +6 MB
    unsigned short* fb = wT + (int64_t)N3_DIM * K_DIM;          // +64 MB, f bf16
    unsigned short* rb = fb + LBD;                              // +64 MB, r bf16

    // A/B/cin overlay the xb region (xb is dead once gemm completes)
    float* Aarr = (float*)d_ws;                                 // 4 MB
    float* Barr = Aarr + NCHUNK * NBD;                          // 4 MB
    float* cin  = Barr + NCHUNK * NBD;                          // 4 MB

    cvt_x_kernel<<<8192, 256, 0, stream>>>(x, xb);
    cvt_w_kernel<<<768, 256, 0, stream>>>(wgt, wT);
    gemm_kernel<<<NMT * NNT, 512, 0, stream>>>(xb, wT, bias, out + LBD, fb, rb);
    scan_phase1<<<(NCHUNK * NBD) / 256, 256, 0, stream>>>(fb, out + LBD, Aarr, Barr);
    scan_phase2<<<NBD / 256, 256, 0, stream>>>(c0, Aarr, Barr, cin);
    scan_phase3<<<(NCHUNK * NBD) / 256, 256, 0, stream>>>(x, fb, rb, cin, out, out + LBD);
}

// Round 4
// 518.020 us; speedup vs baseline: 2.3735x; 1.0812x over previous
//
#include <hip/hip_runtime.h>
#include <hip/hip_bf16.h>
#include <stdint.h>

#define L_DIM 1024
#define B_DIM 32
#define D_DIM 1024
#define M_DIM (L_DIM * B_DIM)        // 32768 GEMM rows
#define N3_DIM (3 * D_DIM)           // 3072 GEMM cols (u0 | f | r regions)
#define K_DIM D_DIM                  // 1024
#define LBD ((int64_t)L_DIM * B_DIM * D_DIM)  // 33554432
#define NBD (B_DIM * D_DIM)          // 32768 chains
#define NCHUNK 32
#define CLEN 32

// GEMM tiling
#define BM 256
#define BN 256
#define BK 64
#define NMT (M_DIM / BM)   // 128
#define NNT (N3_DIM / BN)  // 12
#define NKT (K_DIM / BK)   // 16
#define NITER (NKT / 2)    // 8

typedef __bf16 bf16_t;
typedef bf16_t bf16x8 __attribute__((ext_vector_type(8)));
typedef float f32x4 __attribute__((ext_vector_type(4)));

// RTNE fp32 -> bf16 bits
__device__ __forceinline__ unsigned short f2bf(float f) {
    union { float f; unsigned u; } v; v.f = f;
    unsigned u = v.u;
    u += 0x7FFFu + ((u >> 16) & 1u);
    return (unsigned short)(u >> 16);
}
__device__ __forceinline__ float bf2f(unsigned short h) {
    union { unsigned u; float f; } v; v.u = ((unsigned)h) << 16;
    return v.f;
}

// ---------------- convert x: fp32 [L,B,D] -> bf16 [M,K] ----------------
__global__ void cvt_x_kernel(const float* __restrict__ x, unsigned short* __restrict__ xb) {
    int64_t i0 = ((int64_t)blockIdx.x * blockDim.x + threadIdx.x) * 4;
    int64_t stride = (int64_t)gridDim.x * blockDim.x * 4;
    for (int64_t i = i0; i < LBD; i += stride) {
        float4 v = *reinterpret_cast<const float4*>(x + i);
        ushort4 o;
        o.x = f2bf(v.x); o.y = f2bf(v.y); o.z = f2bf(v.z); o.w = f2bf(v.w);
        *reinterpret_cast<ushort4*>(xb + i) = o;
    }
}

// ------------- convert weight: [i(1024)][o(1024)][k(3)] fp32 -> wT [n=k*1024+o][i] bf16 -------------
__global__ void cvt_w_kernel(const float* __restrict__ w, unsigned short* __restrict__ wT) {
    __shared__ float tile[64][65];
    int bid = blockIdx.x;               // 768 = 3(k) * 16(o-tiles) * 16(i-tiles)
    int k  = bid >> 8;
    int o0 = ((bid >> 4) & 15) * 64;
    int i0 = (bid & 15) * 64;
    int t = threadIdx.x;
    {
        int o = t & 63, ib = t >> 6;
        #pragma unroll
        for (int it = 0; it < 16; ++it) {
            int i = ib + it * 4;
            tile[o][i] = w[((int64_t)(i0 + i) * 1024 + (o0 + o)) * 3 + k];
        }
    }
    __syncthreads();
    {
        int i = t & 63, ob = t >> 6;
        #pragma unroll
        for (int ot = 0; ot < 16; ++ot) {
            int o = ob + ot * 4;
            wT[(int64_t)(k * 1024 + o0 + o) * 1024 + (i0 + i)] = f2bf(tile[o][i]);
        }
    }
}

// ---------------- GEMM: 256x256 tile, 8 waves, 8-phase dbuf schedule (T2+T3+T4+T5) ----------------
__device__ __forceinline__ void gload_lds16(const void* g, void* l) {
    __builtin_amdgcn_global_load_lds(
        (const __attribute__((address_space(1))) unsigned int*)g,
        (__attribute__((address_space(3))) unsigned int*)l,
        16, 0, 0);
}

#define BARRIER() do { asm volatile("" ::: "memory"); __builtin_amdgcn_s_barrier(); asm volatile("" ::: "memory"); } while (0)
#define WAIT_LGKM0() asm volatile("s_waitcnt lgkmcnt(0)" ::: "memory")
#define WAIT_LGKM8() asm volatile("s_waitcnt lgkmcnt(8)" ::: "memory")
#define VMCNT(n) asm volatile("s_waitcnt vmcnt(" #n ")" ::: "memory")

__global__ __launch_bounds__(512, 2) void gemm_kernel(
    const unsigned short* __restrict__ A,    // [32768][1024] bf16 bits
    const unsigned short* __restrict__ Bt,   // [3072][1024] bf16 bits
    const float* __restrict__ bias,          // [2048]
    float* __restrict__ u0_out,              // d_out + LBD: u0 fp32
    unsigned short* __restrict__ fb,         // ws: f bf16
    unsigned short* __restrict__ rb)         // ws: r bf16
{
    // 128 KiB: [buf][half][128 rows][64 cols] for A (M-halves) and B (N-halves)
    __shared__ __align__(16) unsigned short a_lds[2][2][128 * 64];
    __shared__ __align__(16) unsigned short b_lds[2][2][128 * 64];

    int bid = blockIdx.x;
    int swz = (bid & 7) * (NMT * NNT / 8) + (bid >> 3);   // 1536 % 8 == 0 -> bijective
    int nt = swz % NNT, mt = swz / NNT;
    int m0 = mt * BM, n0 = nt * BN;

    int tid = threadIdx.x;
    int w = tid >> 6, lane = tid & 63;
    int wm = w >> 2, wn = w & 3;           // 2(M) x 4(N) wave grid
    int l15 = lane & 15, l4 = lane >> 4;
    int pcx = l15 & 7;                     // row&7 for read-side XOR swizzle

    // staging: 2 x gload_lds16 per half-tile per thread; source col pre-swizzled
    int srow = w * 8 + (lane >> 3);
    int scol = ((lane & 7) ^ ((lane >> 3) & 7)) << 3;
    const unsigned short* Asrc = A  + (int64_t)(m0 + srow) * K_DIM + scol;
    const unsigned short* Bsrc = Bt + (int64_t)(n0 + srow) * K_DIM + scol;
    unsigned short* dstA = &a_lds[0][0][0] + w * 8 * 64;   // lane adds 16B linearly
    unsigned short* dstB = &b_lds[0][0][0] + w * 8 * 64;

    auto stageA = [&](int buf, int half, int kt) {
        if (kt >= NKT) return;
        const unsigned short* s = Asrc + (int64_t)half * 128 * K_DIM + kt * BK;
        unsigned short* d = dstA + (buf * 2 + half) * (128 * 64);
        gload_lds16(s, d);
        gload_lds16(s + (int64_t)64 * K_DIM, d + 64 * 64);
    };
    auto stageB = [&](int buf, int half, int kt) {
        if (kt >= NKT) return;
        const unsigned short* s = Bsrc + (int64_t)half * 128 * K_DIM + kt * BK;
        unsigned short* d = dstB + (buf * 2 + half) * (128 * 64);
        gload_lds16(s, d);
        gload_lds16(s + (int64_t)64 * K_DIM, d + 64 * 64);
    };

    auto rdA_ = [&](int buf, int mh, int im, int ks) -> bf16x8 {
        int rr = wm * 64 + im * 16 + l15;
        int pc = ((ks * 4 + l4) ^ pcx) << 3;
        return *reinterpret_cast<const bf16x8*>(&a_lds[buf][mh][rr * 64 + pc]);
    };
    auto rdB_ = [&](int buf, int nh, int jn, int ks) -> bf16x8 {
        int rr = wn * 32 + jn * 16 + l15;
        int pc = ((ks * 4 + l4) ^ pcx) << 3;
        return *reinterpret_cast<const bf16x8*>(&b_lds[buf][nh][rr * 64 + pc]);
    };

    f32x4 acc[8][4];
    #pragma unroll
    for (int i = 0; i < 8; ++i)
        #pragma unroll
        for (int j = 0; j < 4; ++j) acc[i][j] = (f32x4){0.f, 0.f, 0.f, 0.f};

    bf16x8 af[4][2], b0[2][2], b1[2][2];

#define QUAD(MH, NH, BB)                                                            \
    do {                                                                            \
        __builtin_amdgcn_s_setprio(1);                                              \
        _Pragma("unroll")                                                           \
        for (int im = 0; im < 4; ++im)                                              \
            _Pragma("unroll")                                                       \
            for (int jn = 0; jn < 2; ++jn)                                          \
                _Pragma("unroll")                                                   \
                for (int ks = 0; ks < 2; ++ks)                                      \
                    acc[(MH)*4 + im][(NH)*2 + jn] =                                 \
                        __builtin_amdgcn_mfma_f32_16x16x32_bf16(                    \
                            af[im][ks], BB[jn][ks], acc[(MH)*4 + im][(NH)*2 + jn],  \
                            0, 0, 0);                                               \
        __builtin_amdgcn_s_setprio(0);                                              \
    } while (0)

    // prologue: tile0 fully (buf0: A0,B0,B1,A1) + tile1 partial (buf1: A0,B0,B1)
    stageA(0, 0, 0);
    stageB(0, 0, 0);
    stageB(0, 1, 0);
    stageA(0, 1, 0);
    stageA(1, 0, 1);
    stageB(1, 0, 1);
    stageB(1, 1, 1);
    VMCNT(6);          // tile0's 8 loads landed; tile1's 6 may be in flight
    BARRIER();

    for (int t = 0; t < NITER; ++t) {
        int t2 = t * 2;
        // ---- P1: read buf0 A0+B0 (12), stage buf1.A1 <- tile t2+1, MFMA (0,0)
        #pragma unroll
        for (int im = 0; im < 4; ++im) { af[im][0] = rdA_(0, 0, im, 0); af[im][1] = rdA_(0, 0, im, 1); }
        #pragma unroll
        for (int jn = 0; jn < 2; ++jn) { b0[jn][0] = rdB_(0, 0, jn, 0); b0[jn][1] = rdB_(0, 0, jn, 1); }
        stageA(1, 1, t2 + 1);
        WAIT_LGKM8();
        BARRIER();
        WAIT_LGKM0();
        QUAD(0, 0, b0);
        BARRIER();
        // ---- P2: read buf0 B1 (4), stage buf0.A0 <- t2+2, MFMA (0,1)
        #pragma unroll
        for (int jn = 0; jn < 2; ++jn) { b1[jn][0] = rdB_(0, 1, jn, 0); b1[jn][1] = rdB_(0, 1, jn, 1); }
        stageA(0, 0, t2 + 2);
        BARRIER();
        WAIT_LGKM0();
        QUAD(0, 1, b1);
        BARRIER();
        // ---- P3: read buf0 A1 (8), stage buf0.B0 <- t2+2, MFMA (1,0)
        #pragma unroll
        for (int im = 0; im < 4; ++im) { af[im][0] = rdA_(0, 1, im, 0); af[im][1] = rdA_(0, 1, im, 1); }
        stageB(0, 0, t2 + 2);
        BARRIER();
        WAIT_LGKM0();
        QUAD(1, 0, b0);
        BARRIER();
        // ---- P4: stage buf0.B1 <- t2+2, vmcnt, MFMA (1,1)
        stageB(0, 1, t2 + 2);
        if (t < NITER - 1) { VMCNT(6); } else { VMCNT(0); }
        BARRIER();
        QUAD(1, 1, b1);
        BARRIER();
        // ---- P5: read buf1 A0+B0 (12), stage buf0.A1 <- t2+2, MFMA (0,0)
        #pragma unroll
        for (int im = 0; im < 4; ++im) { af[im][0] = rdA_(1, 0, im, 0); af[im][1] = rdA_(1, 0, im, 1); }
        #pragma unroll
        for (int jn = 0; jn < 2; ++jn) { b0[jn][0] = rdB_(1, 0, jn, 0); b0[jn][1] = rdB_(1, 0, jn, 1); }
        stageA(0, 1, t2 + 2);
        WAIT_LGKM8();
        BARRIER();
        WAIT_LGKM0();
        QUAD(0, 0, b0);
        BARRIER();
        // ---- P6: read buf1 B1 (4), stage buf1.A0 <- t2+3, MFMA (0,1)
        #pragma unroll
        for (int jn = 0; jn < 2; ++jn) { b1[jn][0] = rdB_(1, 1, jn, 0); b1[jn][1] = rdB_(1, 1, jn, 1); }
        stageA(1, 0, t2 + 3);
        BARRIER();
        WAIT_LGKM0();
        QUAD(0, 1, b1);
        BARRIER();
        // ---- P7: read buf1 A1 (8), stage buf1.B0 <- t2+3, MFMA (1,0)
        #pragma unroll
        for (int im = 0; im < 4; ++im) { af[im][0] = rdA_(1, 1, im, 0); af[im][1] = rdA_(1, 1, im, 1); }
        stageB(1, 0, t2 + 3);
        BARRIER();
        WAIT_LGKM0();
        QUAD(1, 0, b0);
        BARRIER();
        // ---- P8: stage buf1.B1 <- t2+3, vmcnt, MFMA (1,1)
        stageB(1, 1, t2 + 3);
        if (t < NITER - 1) { VMCNT(6); } else { VMCNT(0); }
        BARRIER();
        QUAD(1, 1, b1);
        BARRIER();
    }

    // epilogue: region uniform per block (n0 multiple of 256)
    int region = n0 >> 10;
    #pragma unroll
    for (int i = 0; i < 8; ++i) {
        int mh = i >> 2, im = i & 3;
        #pragma unroll
        for (int j = 0; j < 4; ++j) {
            int nh = j >> 1, jn = j & 1;
            f32x4 v = acc[i][j];
            int row0 = m0 + mh * 128 + wm * 64 + im * 16 + l4 * 4;
            int col  = (n0 + nh * 128 + wn * 32 + jn * 16 + l15) & 1023;
            #pragma unroll
            for (int jj = 0; jj < 4; ++jj) {
                int64_t idx = (int64_t)(row0 + jj) * 1024 + col;
                float val = v[jj];
                if (region == 0) {
                    u0_out[idx] = val;
                } else if (region == 1) {
                    fb[idx] = f2bf(1.0f / (1.0f + __expf(-(val + bias[col]))));
                } else {
                    rb[idx] = f2bf(1.0f / (1.0f + __expf(-(val + bias[1024 + col]))));
                }
            }
        }
    }
#undef QUAD
}

// ---------------- chunked parallel scan ----------------
// c_t = f_t*c_{t-1} + (1-f_t)*u0_t. Chunk transfer: c_out = A*c_in + B.

__global__ void scan_phase1(const unsigned short* __restrict__ fb,
                            const float* __restrict__ u0_arr,
                            float* __restrict__ Aout, float* __restrict__ Bout) {
    int t = blockIdx.x * blockDim.x + threadIdx.x;   // chunk*NBD + idx
    int idx = t & (NBD - 1);
    int chunk = t >> 15;
    int64_t base = (int64_t)chunk * CLEN * NBD + idx;
    float Ap = 1.0f, Bv = 0.0f;
    #pragma unroll 8
    for (int i = 0; i < CLEN; ++i, base += NBD) {
        float f = bf2f(fb[base]);
        float u0 = u0_arr[base];
        Bv = u0 + f * (Bv - u0);
        Ap *= f;
    }
    Aout[t] = Ap; Bout[t] = Bv;
}

__global__ void scan_phase2(const float* __restrict__ c0, const float* __restrict__ Aarr,
                            const float* __restrict__ Barr, float* __restrict__ cin) {
    int idx = blockIdx.x * blockDim.x + threadIdx.x; // 0..NBD-1
    float c = c0[idx];
    #pragma unroll
    for (int ch = 0; ch < NCHUNK; ++ch) {
        cin[ch * NBD + idx] = c;
        c = Aarr[ch * NBD + idx] * c + Barr[ch * NBD + idx];
    }
}

__global__ void scan_phase3(const float* __restrict__ x,
                            const unsigned short* __restrict__ fb,
                            const unsigned short* __restrict__ rb,
                            const float* __restrict__ cin,
                            float* __restrict__ out_h, float* __restrict__ out_c) {
    int t = blockIdx.x * blockDim.x + threadIdx.x;
    int idx = t & (NBD - 1);
    int chunk = t >> 15;
    float c = cin[t];
    int64_t base = (int64_t)chunk * CLEN * NBD + idx;
    #pragma unroll 4
    for (int i = 0; i < CLEN; ++i, base += NBD) {
        float f  = bf2f(fb[base]);
        float u0 = out_c[base];     // u0 written by gemm epilogue
        c = u0 + f * (c - u0);      // f*c + (1-f)*u0
        out_c[base] = c;
        float e = __expf(2.0f * c); // tanh via exp; |c| bounded so no overflow
        float g = (e - 1.0f) / (e + 1.0f);
        float r = bf2f(rb[base]);
        float xv = x[base];
        out_h[base] = xv + r * (g - xv);
    }
}

extern "C" void kernel_launch(void* const* d_in, const int* in_sizes, int n_in,
                              void* d_out, int out_size, void* d_ws, size_t ws_size,
                              hipStream_t stream) {
    const float* x    = (const float*)d_in[0];
    const float* c0   = (const float*)d_in[1];
    const float* wgt  = (const float*)d_in[2];
    const float* bias = (const float*)d_in[3];
    float* out = (float*)d_out;

    unsigned short* xb = (unsigned short*)d_ws;                 // 64 MB (dead after gemm)
    unsigned short* wT = xb + (int64_t)M_DIM * K_DIM;           // +6 MB
    unsigned short* fb = wT + (int64_t)N3_DIM * K_DIM;          // +64 MB, f bf16
    unsigned short* rb = fb + LBD;                              // +64 MB, r bf16

    // A/B/cin overlay the xb region (xb is dead once gemm completes)
    float* Aarr = (float*)d_ws;                                 // 4 MB
    float* Barr = Aarr + NCHUNK * NBD;                          // 4 MB
    float* cin  = Barr + NCHUNK * NBD;                          // 4 MB

    cvt_x_kernel<<<8192, 256, 0, stream>>>(x, xb);
    cvt_w_kernel<<<768, 256, 0, stream>>>(wgt, wT);
    gemm_kernel<<<NMT * NNT, 512, 0, stream>>>(xb, wT, bias, out + LBD, fb, rb);
    scan_phase1<<<(NCHUNK * NBD) / 256, 256, 0, stream>>>(fb, out + LBD, Aarr, Barr);
    scan_phase2<<<NBD / 256, 256, 0, stream>>>(c0, Aarr, Barr, cin);
    scan_phase3<<<(NCHUNK * NBD) / 256, 256, 0, stream>>>(x, fb, rb, cin, out, out + LBD);
}